// Round 7
// baseline (2186.114 us; speedup 1.0000x reference)
//
#include <hip/hip_runtime.h>
#include <hip/hip_bf16.h>
#include <stdint.h>

#define IGNORE_INDEX (-100)

typedef float f32x4 __attribute__((ext_vector_type(4)));
typedef int i32x4 __attribute__((ext_vector_type(4)));
typedef int i32x8 __attribute__((ext_vector_type(8)));

constexpr int NTOK = 4096;
constexpr int HID  = 2048;
constexpr int VOC  = 32000;
constexpr int BM = 128, BN = 128, BKB = 128;   // BKB = K-bytes per tile (fp8)
constexpr int NT_N = VOC / BN;   // 250 n-tiles
constexpr int NT_M = NTOK / BM;  // 32 m-tiles

// Pre-scales folded out via MFMA E8M0 block-scales:
//   X stored as fp8(X * 8)   -> scale_a byte = 127-3 = 124 (2^-3)
//   W stored as fp8(W * 64)  -> scale_b byte = 127-6 = 121 (2^-6)
#define XSCALE 8.0f
#define WSCALE 64.0f
#define SCALE_A 0x7C7C7C7C   // 124 replicated (opsel-proof)
#define SCALE_B 0x79797979   // 121 replicated

// ---- ws layout (bytes) ----
// Wf8  @ 0         : 32000*2048 = 65,536,000
// Xf8  @ 65536000  :  4096*2048 =  8,388,608
// pmax @ 73924608  : 250*4096*4 =  4,096,000   ([ntile][row])
// psum @ 78020608  : 250*4096*4 =  4,096,000
// xt   @ 82116608  :     4096*4
// loss @ 82132992  :     4096*4

__global__ void cvt8_kernel(const float* __restrict__ src, uint2* __restrict__ dst,
                            size_t n8, float scale) {
  size_t i = (size_t)blockIdx.x * blockDim.x + threadIdx.x;
  size_t stride = (size_t)gridDim.x * blockDim.x;
  const float4* s4 = reinterpret_cast<const float4*>(src);
  for (; i < n8; i += stride) {
    float4 a = s4[2 * i];
    float4 b = s4[2 * i + 1];
    int lo = __builtin_amdgcn_cvt_pk_fp8_f32(a.x * scale, a.y * scale, 0, false);
    lo = __builtin_amdgcn_cvt_pk_fp8_f32(a.z * scale, a.w * scale, lo, true);
    int hi = __builtin_amdgcn_cvt_pk_fp8_f32(b.x * scale, b.y * scale, 0, false);
    hi = __builtin_amdgcn_cvt_pk_fp8_f32(b.z * scale, b.w * scale, hi, true);
    dst[i] = make_uint2((unsigned)lo, (unsigned)hi);
  }
}

// x_t[row] = dot(X[row], W[target[row]]) + bias[target[row]]   (fp32, exact)
__global__ void xt_kernel(const float* __restrict__ X, const float* __restrict__ W,
                          const float* __restrict__ bias, const int* __restrict__ tgt,
                          float* __restrict__ xt) {
  int row = blockIdx.x * 4 + (threadIdx.x >> 6);
  int lane = threadIdx.x & 63;
  if (row >= NTOK) return;
  int t = tgt[row];
  if (t < 0 || t >= VOC) { if (lane == 0) xt[row] = 0.0f; return; }
  const float4* xr = reinterpret_cast<const float4*>(X + (size_t)row * HID);
  const float4* wr = reinterpret_cast<const float4*>(W + (size_t)t * HID);
  float s = 0.0f;
  for (int i = lane; i < HID / 4; i += 64) {
    float4 a = xr[i], b = wr[i];
    s += a.x * b.x + a.y * b.y + a.z * b.z + a.w * b.w;
  }
#pragma unroll
  for (int d = 1; d < 64; d <<= 1) s += __shfl_xor(s, d);
  if (lane == 0) xt[row] = s + bias[t];
}

// Fused MX-fp8 GEMM (logits tile) + per-row (max, sumexp) partials.
// m97 structure (R6-verified on this problem): 128x128 tile, 4 waves 2x2,
// single-buffered LDS, 2 __syncthreads/K-iter, global_load_lds w=16, 3 blocks/CU.
// dtype: fp8 e4m3, K-tile = 128 bytes, mfma_scale_f32_16x16x128_f8f6f4 (16 iters).
// Swizzle (both-sides, 16B chunks, 8/row): stored chunk s = c ^ (row&7);
// 16 lanes -> 8 bank-groups x 2 => conflict-free (same family as R6's measured 0).
// Within-lane k-permutation is harmless: A and B share the same reg->k mapping,
// so the MFMA dot-product is invariant; uniform scales are k-block-agnostic.
__global__ __launch_bounds__(256, 3) void gemm_lse_kernel(
    const uint8_t* __restrict__ Xf8, const uint8_t* __restrict__ Wf8,
    const float* __restrict__ bias,
    float* __restrict__ pmax, float* __restrict__ psum) {
  __shared__ __align__(16) uint8_t As[BM * BKB];   // 16 KB
  __shared__ __align__(16) uint8_t Bs[BN * BKB];   // 16 KB
  __shared__ float redM[2][BM];
  __shared__ float redS[2][BM];

  // XCD-chunked swizzle, mtile-fastest (8000 % 8 == 0, bijective)
  const int nwg = NT_M * NT_N;           // 8000
  const int xcd = blockIdx.x & 7;
  const int pos = blockIdx.x >> 3;
  const int wgid = xcd * (nwg >> 3) + pos;
  const int mtile = wgid & (NT_M - 1);   // 32 consecutive blocks share W panel
  const int ntile = wgid >> 5;
  const int mbase = mtile * BM;
  const int nbase = ntile * BN;

  const int tid = threadIdx.x;
  const int w = tid >> 6;                // 0..3
  const int lane = tid & 63;
  const int wr = w >> 1, wc = w & 1;     // wave -> 64x64 output sub-tile
  const int l15 = lane & 15;
  const int kgrp = lane >> 4;            // 0..3

  // ---- staging: linear LDS dest, inverse-swizzled global source ----
  // issue j: LDS bytes [j*4096 + tid*16, +16) -> row = j*32 + (tid>>3),
  // stored slot s = tid&7 holds global 16B-chunk c = s ^ (row&7) = s ^ ((tid>>3)&7).
  const int srow = tid >> 3;                          // 0..31
  const int csrc = (tid & 7) ^ ((tid >> 3) & 7);
  const uint8_t* aSt = Xf8 + (size_t)(mbase + srow) * HID + csrc * 16;
  const uint8_t* bSt = Wf8 + (size_t)(nbase + srow) * HID + csrc * 16;

  // ds_read: row r, global chunks (2*kgrp, 2*kgrp+1) stored at chunk ^ (r&7);
  // r&7 = l15&7 for our rows (wr*64, wc*64, mi*16 all ≡ 0 mod 8).
  const int s0 = (2 * kgrp) ^ (l15 & 7);
  const int s1 = s0 ^ 1;
  const int arow0 = wr * 64 + l15;
  const int brow0 = wc * 64 + l15;

  f32x4 acc[4][4];
#pragma unroll
  for (int mi = 0; mi < 4; ++mi)
#pragma unroll
    for (int ni = 0; ni < 4; ++ni)
#pragma unroll
      for (int j = 0; j < 4; ++j) acc[mi][ni][j] = 0.0f;

  float bv[4];
#pragma unroll
  for (int ni = 0; ni < 4; ++ni) bv[ni] = bias[nbase + wc * 64 + ni * 16 + l15];

#define GLDS(SRC, DST)                                                              \
  __builtin_amdgcn_global_load_lds((const __attribute__((address_space(1))) void*)(SRC), \
                                   (__attribute__((address_space(3))) void*)(DST), 16, 0, 0)

  for (int k0 = 0; k0 < HID; k0 += BKB) {
    __syncthreads();
#pragma unroll
    for (int j = 0; j < 4; ++j) {
      GLDS(aSt + k0 + (size_t)j * 32 * HID, As + j * 4096 + tid * 16);
      GLDS(bSt + k0 + (size_t)j * 32 * HID, Bs + j * 4096 + tid * 16);
    }
    __syncthreads();

    i32x8 af[4], bg[4];
#pragma unroll
    for (int mi = 0; mi < 4; ++mi) {
      const uint8_t* p = As + (arow0 + mi * 16) * BKB;
      i32x4 lo = *reinterpret_cast<const i32x4*>(p + s0 * 16);
      i32x4 hi = *reinterpret_cast<const i32x4*>(p + s1 * 16);
      af[mi] = __builtin_shufflevector(lo, hi, 0, 1, 2, 3, 4, 5, 6, 7);
    }
#pragma unroll
    for (int ni = 0; ni < 4; ++ni) {
      const uint8_t* p = Bs + (brow0 + ni * 16) * BKB;
      i32x4 lo = *reinterpret_cast<const i32x4*>(p + s0 * 16);
      i32x4 hi = *reinterpret_cast<const i32x4*>(p + s1 * 16);
      bg[ni] = __builtin_shufflevector(lo, hi, 0, 1, 2, 3, 4, 5, 6, 7);
    }
#pragma unroll
    for (int mi = 0; mi < 4; ++mi)
#pragma unroll
      for (int ni = 0; ni < 4; ++ni)
        acc[mi][ni] = __builtin_amdgcn_mfma_scale_f32_16x16x128_f8f6f4(
            af[mi], bg[ni], acc[mi][ni], 0 /*cbsz: fp8*/, 0 /*blgp: fp8*/,
            0, SCALE_A, 0, SCALE_B);
  }
#undef GLDS

  // ---- epilogue: per-row (max, sumexp) over this block's 128 cols ----
  // C frag: col = l15 (B row), row = kgrp*4 + j (A row) — shape-determined,
  // verified R1-R6
#pragma unroll
  for (int mi = 0; mi < 4; ++mi) {
#pragma unroll
    for (int j = 0; j < 4; ++j) {
      float v0 = acc[mi][0][j] + bv[0];
      float v1 = acc[mi][1][j] + bv[1];
      float v2 = acc[mi][2][j] + bv[2];
      float v3 = acc[mi][3][j] + bv[3];
      float mx = fmaxf(fmaxf(v0, v1), fmaxf(v2, v3));
#pragma unroll
      for (int d = 1; d < 16; d <<= 1) mx = fmaxf(mx, __shfl_xor(mx, d));
      float s = __expf(v0 - mx) + __expf(v1 - mx) + __expf(v2 - mx) + __expf(v3 - mx);
#pragma unroll
      for (int d = 1; d < 16; d <<= 1) s += __shfl_xor(s, d);
      if (l15 == 0) {
        int lr = wr * 64 + mi * 16 + kgrp * 4 + j;
        redM[wc][lr] = mx;
        redS[wc][lr] = s;
      }
    }
  }
  __syncthreads();
  if (tid < BM) {
    float m0 = redM[0][tid], m1 = redM[1][tid];
    float M = fmaxf(m0, m1);
    float S = __expf(m0 - M) * redS[0][tid] + __expf(m1 - M) * redS[1][tid];
    size_t row = (size_t)mbase + tid;
    pmax[(size_t)ntile * NTOK + row] = M;   // coalesced over tid
    psum[(size_t)ntile * NTOK + row] = S;
  }
}

// merge 250 partials per row -> lse -> per-row loss
__global__ void lse_kernel(const float* __restrict__ pmax, const float* __restrict__ psum,
                           const float* __restrict__ xt, const int* __restrict__ tgt,
                           float* __restrict__ loss) {
  int row = blockIdx.x * 4 + (threadIdx.x >> 6);
  int lane = threadIdx.x & 63;
  if (row >= NTOK) return;
  float M = -3.4e38f;
  for (int i = lane; i < NT_N; i += 64) M = fmaxf(M, pmax[(size_t)i * NTOK + row]);
#pragma unroll
  for (int d = 1; d < 64; d <<= 1) M = fmaxf(M, __shfl_xor(M, d));
  float S = 0.0f;
  for (int i = lane; i < NT_N; i += 64)
    S += __expf(pmax[(size_t)i * NTOK + row] - M) * psum[(size_t)i * NTOK + row];
#pragma unroll
  for (int d = 1; d < 64; d <<= 1) S += __shfl_xor(S, d);
  if (lane == 0) {
    int tg = tgt[row];
    bool valid = (tg != IGNORE_INDEX);
    float lse = M + __logf(S);
    loss[row] = valid ? (lse - xt[row]) : 0.0f;
  }
}

__global__ void final_kernel(const float* __restrict__ loss, const int* __restrict__ tgt,
                             float* __restrict__ out) {
  __shared__ float shs[256];
  __shared__ float shc[256];
  int tid = threadIdx.x;
  float s = 0.0f, c = 0.0f;
  for (int i = tid; i < NTOK; i += 256) {
    s += loss[i];
    c += (tgt[i] != IGNORE_INDEX) ? 1.0f : 0.0f;
  }
  shs[tid] = s; shc[tid] = c;
  __syncthreads();
  for (int off = 128; off > 0; off >>= 1) {
    if (tid < off) { shs[tid] += shs[tid + off]; shc[tid] += shc[tid + off]; }
    __syncthreads();
  }
  if (tid == 0) out[0] = shs[0] / fmaxf(shc[0], 1.0f);
}

extern "C" void kernel_launch(void* const* d_in, const int* in_sizes, int n_in,
                              void* d_out, int out_size, void* d_ws, size_t ws_size,
                              hipStream_t stream) {
  const float* W    = (const float*)d_in[0];  // [32000][2048]
  const float* X    = (const float*)d_in[1];  // [4096][2048]
  const int*   tgt  = (const int*)d_in[2];    // [4096]
  const float* bias = (const float*)d_in[3];  // [32000]
  float* out = (float*)d_out;

  char* ws = (char*)d_ws;
  uint8_t* Wf8 = (uint8_t*)(ws);
  uint8_t* Xf8 = (uint8_t*)(ws + 65536000);
  float* pmax  = (float*)  (ws + 73924608);
  float* psum  = (float*)  (ws + 78020608);
  float* xt    = (float*)  (ws + 82116608);
  float* loss  = (float*)  (ws + 82132992);

  cvt8_kernel<<<2048, 256, 0, stream>>>(W, (uint2*)Wf8, (size_t)VOC * HID / 8, WSCALE);
  cvt8_kernel<<<1024, 256, 0, stream>>>(X, (uint2*)Xf8, (size_t)NTOK * HID / 8, XSCALE);
  xt_kernel<<<NTOK / 4, 256, 0, stream>>>(X, W, bias, tgt, xt);
  gemm_lse_kernel<<<NT_M * NT_N, 256, 0, stream>>>(Xf8, Wf8, bias, pmax, psum);
  lse_kernel<<<NTOK / 4, 256, 0, stream>>>(pmax, psum, xt, tgt, loss);
  final_kernel<<<1, 256, 0, stream>>>(loss, tgt, out);
}

// Round 8
// 491.862 us; speedup vs baseline: 4.4446x; 4.4446x over previous
//
#include <hip/hip_runtime.h>
#include <hip/hip_bf16.h>
#include <stdint.h>

#define IGNORE_INDEX (-100)

typedef float f32x4 __attribute__((ext_vector_type(4)));
typedef long i64x2 __attribute__((ext_vector_type(2)));

constexpr int NTOK = 4096;
constexpr int HID  = 2048;
constexpr int VOC  = 32000;
constexpr int BM = 128, BN = 128, BKB = 64;   // BKB = K-bytes per tile (64 fp8)
constexpr int NT_N = VOC / BN;   // 250 n-tiles
constexpr int NT_M = NTOK / BM;  // 32 m-tiles

// Pre-scales (avoid e4m3 denormals), descaled in epilogue:
//   X stored as fp8(X * 8), W stored as fp8(W * 64)  ->  logits = acc/512 + bias
#define XSCALE 8.0f
#define WSCALE 64.0f
#define INV_SCALE (1.0f / 512.0f)

// ---- ws layout (bytes) ----
// Wf8  @ 0         : 32000*2048 = 65,536,000
// Xf8  @ 65536000  :  4096*2048 =  8,388,608
// pmax @ 73924608  : 250*4096*4 =  4,096,000   ([ntile][row])
// psum @ 78020608  : 250*4096*4 =  4,096,000
// xt   @ 82116608  :     4096*4
// loss @ 82132992  :     4096*4

__global__ void cvt8_kernel(const float* __restrict__ src, uint2* __restrict__ dst,
                            size_t n8, float scale) {
  size_t i = (size_t)blockIdx.x * blockDim.x + threadIdx.x;
  size_t stride = (size_t)gridDim.x * blockDim.x;
  const float4* s4 = reinterpret_cast<const float4*>(src);
  for (; i < n8; i += stride) {
    float4 a = s4[2 * i];
    float4 b = s4[2 * i + 1];
    int lo = __builtin_amdgcn_cvt_pk_fp8_f32(a.x * scale, a.y * scale, 0, false);
    lo = __builtin_amdgcn_cvt_pk_fp8_f32(a.z * scale, a.w * scale, lo, true);
    int hi = __builtin_amdgcn_cvt_pk_fp8_f32(b.x * scale, b.y * scale, 0, false);
    hi = __builtin_amdgcn_cvt_pk_fp8_f32(b.z * scale, b.w * scale, hi, true);
    dst[i] = make_uint2((unsigned)lo, (unsigned)hi);
  }
}

// x_t[row] = dot(X[row], W[target[row]]) + bias[target[row]]   (fp32, exact)
__global__ void xt_kernel(const float* __restrict__ X, const float* __restrict__ W,
                          const float* __restrict__ bias, const int* __restrict__ tgt,
                          float* __restrict__ xt) {
  int row = blockIdx.x * 4 + (threadIdx.x >> 6);
  int lane = threadIdx.x & 63;
  if (row >= NTOK) return;
  int t = tgt[row];
  if (t < 0 || t >= VOC) { if (lane == 0) xt[row] = 0.0f; return; }
  const float4* xr = reinterpret_cast<const float4*>(X + (size_t)row * HID);
  const float4* wr = reinterpret_cast<const float4*>(W + (size_t)t * HID);
  float s = 0.0f;
  for (int i = lane; i < HID / 4; i += 64) {
    float4 a = xr[i], b = wr[i];
    s += a.x * b.x + a.y * b.y + a.z * b.z + a.w * b.w;
  }
#pragma unroll
  for (int d = 1; d < 64; d <<= 1) s += __shfl_xor(s, d);
  if (lane == 0) xt[row] = s + bias[t];
}

// Fused fp8 GEMM (logits tile) + per-row (max, sumexp) partials.
// R6's m97 structure with BYTE-IDENTICAL LDS geometry (measured 0 conflicts,
// 3 blocks/CU): 128x128 tile, 4 waves 2x2, single-buffered 16KB LDS,
// 2 __syncthreads/K-iter, global_load_lds w=16. Rows are 64B = 64 fp8 = one
// K-tile; 32 K-iters (half of R6's barriers/staging).
// Each lane's b128 = 16 fp8 = lo/hi operands of TWO mfma_f32_16x16x32_fp8_fp8
// k-steps. The induced K-permutation is identical for A and B => dot invariant.
// Swizzle (both-sides): stored 16B-chunk s = c ^ ((row>>1)&3), inverse on
// global src, linear LDS dest (R4/R6 measured-zero family).
__global__ __launch_bounds__(256, 3) void gemm_lse_kernel(
    const uint8_t* __restrict__ Xf8, const uint8_t* __restrict__ Wf8,
    const float* __restrict__ bias,
    float* __restrict__ pmax, float* __restrict__ psum) {
  __shared__ __align__(16) uint8_t As[BM * BKB];   // 8 KB
  __shared__ __align__(16) uint8_t Bs[BN * BKB];   // 8 KB
  __shared__ float redM[2][BM];
  __shared__ float redS[2][BM];

  // XCD-chunked swizzle, mtile-fastest (8000 % 8 == 0, bijective)
  const int nwg = NT_M * NT_N;           // 8000
  const int xcd = blockIdx.x & 7;
  const int pos = blockIdx.x >> 3;
  const int wgid = xcd * (nwg >> 3) + pos;
  const int mtile = wgid & (NT_M - 1);   // 32 consecutive blocks share W panel
  const int ntile = wgid >> 5;
  const int mbase = mtile * BM;
  const int nbase = ntile * BN;

  const int tid = threadIdx.x;
  const int w = tid >> 6;                // 0..3
  const int lane = tid & 63;
  const int wr = w >> 1, wc = w & 1;     // wave -> 64x64 output sub-tile
  const int l15 = lane & 15;
  const int kgrp = lane >> 4;            // 0..3

  // ---- staging: linear LDS dest, inverse-swizzled global source ----
  // issue j: LDS bytes [j*4096 + tid*16, +16) -> row = j*64 + (tid>>2),
  // stored slot s = tid&3 holds global 16B-chunk c = s ^ ((row>>1)&3)
  //                                               = s ^ ((tid>>3)&3).
  const int srow = tid >> 2;                          // 0..63
  const int csrc = (tid & 3) ^ ((tid >> 3) & 3);
  const uint8_t* aSt0 = Xf8 + (size_t)(mbase + srow) * HID + csrc * 16;
  const uint8_t* aSt1 = aSt0 + (size_t)64 * HID;      // j=1: +64 rows
  const uint8_t* bSt0 = Wf8 + (size_t)(nbase + srow) * HID + csrc * 16;
  const uint8_t* bSt1 = bSt0 + (size_t)64 * HID;

  // ds_read: row r, global chunk kgrp stored at kgrp ^ ((r>>1)&3);
  // (r>>1)&3 = (l15>>1)&3 for our rows (wr*64, wc*64, mi*16 all ≡ 0 mod 16).
  const int swz16 = (kgrp ^ ((l15 >> 1) & 3)) * 16;   // byte offset in row
  const int arow0 = wr * 64 + l15;
  const int brow0 = wc * 64 + l15;

  f32x4 acc[4][4];
#pragma unroll
  for (int mi = 0; mi < 4; ++mi)
#pragma unroll
    for (int ni = 0; ni < 4; ++ni)
#pragma unroll
      for (int j = 0; j < 4; ++j) acc[mi][ni][j] = 0.0f;

  float bv[4];
#pragma unroll
  for (int ni = 0; ni < 4; ++ni) bv[ni] = bias[nbase + wc * 64 + ni * 16 + l15];

#define GLDS(SRC, DST)                                                              \
  __builtin_amdgcn_global_load_lds((const __attribute__((address_space(1))) void*)(SRC), \
                                   (__attribute__((address_space(3))) void*)(DST), 16, 0, 0)

  for (int k0 = 0; k0 < HID; k0 += BKB) {
    __syncthreads();
    GLDS(aSt0 + k0, As + tid * 16);
    GLDS(aSt1 + k0, As + 4096 + tid * 16);
    GLDS(bSt0 + k0, Bs + tid * 16);
    GLDS(bSt1 + k0, Bs + 4096 + tid * 16);
    __syncthreads();

    i64x2 af[4], bg[4];
#pragma unroll
    for (int mi = 0; mi < 4; ++mi)
      af[mi] = *reinterpret_cast<const i64x2*>(As + (arow0 + mi * 16) * BKB + swz16);
#pragma unroll
    for (int ni = 0; ni < 4; ++ni)
      bg[ni] = *reinterpret_cast<const i64x2*>(Bs + (brow0 + ni * 16) * BKB + swz16);
#pragma unroll
    for (int mi = 0; mi < 4; ++mi)
#pragma unroll
      for (int ni = 0; ni < 4; ++ni) {
        acc[mi][ni] = __builtin_amdgcn_mfma_f32_16x16x32_fp8_fp8(
            af[mi][0], bg[ni][0], acc[mi][ni], 0, 0, 0);
        acc[mi][ni] = __builtin_amdgcn_mfma_f32_16x16x32_fp8_fp8(
            af[mi][1], bg[ni][1], acc[mi][ni], 0, 0, 0);
      }
  }
#undef GLDS

  // ---- epilogue: per-row (max, sumexp) over this block's 128 cols ----
  // C frag: col = l15 (B row), row = kgrp*4 + j (A row) — verified R1-R6.
  // Descale by 1/512 folded into the bias FMA.
#pragma unroll
  for (int mi = 0; mi < 4; ++mi) {
#pragma unroll
    for (int j = 0; j < 4; ++j) {
      float v0 = fmaf(acc[mi][0][j], INV_SCALE, bv[0]);
      float v1 = fmaf(acc[mi][1][j], INV_SCALE, bv[1]);
      float v2 = fmaf(acc[mi][2][j], INV_SCALE, bv[2]);
      float v3 = fmaf(acc[mi][3][j], INV_SCALE, bv[3]);
      float mx = fmaxf(fmaxf(v0, v1), fmaxf(v2, v3));
#pragma unroll
      for (int d = 1; d < 16; d <<= 1) mx = fmaxf(mx, __shfl_xor(mx, d));
      float s = __expf(v0 - mx) + __expf(v1 - mx) + __expf(v2 - mx) + __expf(v3 - mx);
#pragma unroll
      for (int d = 1; d < 16; d <<= 1) s += __shfl_xor(s, d);
      if (l15 == 0) {
        int lr = wr * 64 + mi * 16 + kgrp * 4 + j;
        redM[wc][lr] = mx;
        redS[wc][lr] = s;
      }
    }
  }
  __syncthreads();
  if (tid < BM) {
    float m0 = redM[0][tid], m1 = redM[1][tid];
    float M = fmaxf(m0, m1);
    float S = __expf(m0 - M) * redS[0][tid] + __expf(m1 - M) * redS[1][tid];
    size_t row = (size_t)mbase + tid;
    pmax[(size_t)ntile * NTOK + row] = M;   // coalesced over tid
    psum[(size_t)ntile * NTOK + row] = S;
  }
}

// merge 250 partials per row -> lse -> per-row loss
__global__ void lse_kernel(const float* __restrict__ pmax, const float* __restrict__ psum,
                           const float* __restrict__ xt, const int* __restrict__ tgt,
                           float* __restrict__ loss) {
  int row = blockIdx.x * 4 + (threadIdx.x >> 6);
  int lane = threadIdx.x & 63;
  if (row >= NTOK) return;
  float M = -3.4e38f;
  for (int i = lane; i < NT_N; i += 64) M = fmaxf(M, pmax[(size_t)i * NTOK + row]);
#pragma unroll
  for (int d = 1; d < 64; d <<= 1) M = fmaxf(M, __shfl_xor(M, d));
  float S = 0.0f;
  for (int i = lane; i < NT_N; i += 64)
    S += __expf(pmax[(size_t)i * NTOK + row] - M) * psum[(size_t)i * NTOK + row];
#pragma unroll
  for (int d = 1; d < 64; d <<= 1) S += __shfl_xor(S, d);
  if (lane == 0) {
    int tg = tgt[row];
    bool valid = (tg != IGNORE_INDEX);
    float lse = M + __logf(S);
    loss[row] = valid ? (lse - xt[row]) : 0.0f;
  }
}

__global__ void final_kernel(const float* __restrict__ loss, const int* __restrict__ tgt,
                             float* __restrict__ out) {
  __shared__ float shs[256];
  __shared__ float shc[256];
  int tid = threadIdx.x;
  float s = 0.0f, c = 0.0f;
  for (int i = tid; i < NTOK; i += 256) {
    s += loss[i];
    c += (tgt[i] != IGNORE_INDEX) ? 1.0f : 0.0f;
  }
  shs[tid] = s; shc[tid] = c;
  __syncthreads();
  for (int off = 128; off > 0; off >>= 1) {
    if (tid < off) { shs[tid] += shs[tid + off]; shc[tid] += shc[tid + off]; }
    __syncthreads();
  }
  if (tid == 0) out[0] = shs[0] / fmaxf(shc[0], 1.0f);
}

extern "C" void kernel_launch(void* const* d_in, const int* in_sizes, int n_in,
                              void* d_out, int out_size, void* d_ws, size_t ws_size,
                              hipStream_t stream) {
  const float* W    = (const float*)d_in[0];  // [32000][2048]
  const float* X    = (const float*)d_in[1];  // [4096][2048]
  const int*   tgt  = (const int*)d_in[2];    // [4096]
  const float* bias = (const float*)d_in[3];  // [32000]
  float* out = (float*)d_out;

  char* ws = (char*)d_ws;
  uint8_t* Wf8 = (uint8_t*)(ws);
  uint8_t* Xf8 = (uint8_t*)(ws + 65536000);
  float* pmax  = (float*)  (ws + 73924608);
  float* psum  = (float*)  (ws + 78020608);
  float* xt    = (float*)  (ws + 82116608);
  float* loss  = (float*)  (ws + 82132992);

  cvt8_kernel<<<2048, 256, 0, stream>>>(W, (uint2*)Wf8, (size_t)VOC * HID / 8, WSCALE);
  cvt8_kernel<<<1024, 256, 0, stream>>>(X, (uint2*)Xf8, (size_t)NTOK * HID / 8, XSCALE);
  xt_kernel<<<NTOK / 4, 256, 0, stream>>>(X, W, bias, tgt, xt);
  gemm_lse_kernel<<<NT_M * NT_N, 256, 0, stream>>>(Xf8, Wf8, bias, pmax, psum);
  lse_kernel<<<NTOK / 4, 256, 0, stream>>>(pmax, psum, xt, tgt, loss);
  final_kernel<<<1, 256, 0, stream>>>(loss, tgt, out);
}